// Round 13
// baseline (344.049 us; speedup 1.0000x reference)
//
#include <hip/hip_runtime.h>

#define N_NODES 8192
#define HDIM    512
#define NEDGE   262144

typedef __attribute__((ext_vector_type(8))) short bf16x8;
typedef __attribute__((ext_vector_type(4))) float f32x4;

__device__ inline unsigned short f2bf(float f) {
  unsigned u = __float_as_uint(f);
  unsigned r = (u + 0x7FFFu + ((u >> 16) & 1u)) >> 16;
  return (unsigned short)r;
}
__device__ inline float bf2f(short s) {
  return __uint_as_float(((unsigned)(unsigned short)s) << 16);
}

__device__ inline void gload16(const void* g, void* l) {
  __builtin_amdgcn_global_load_lds(
      (const __attribute__((address_space(1))) unsigned*)g,
      (__attribute__((address_space(3))) unsigned*)l, 16, 0, 0);
}

__device__ inline void wait_vmcnt_c(int n) {
  if (n == 8)      asm volatile("s_waitcnt vmcnt(8)" ::: "memory");
  else if (n == 4) asm volatile("s_waitcnt vmcnt(4)" ::: "memory");
  else if (n == 3) asm volatile("s_waitcnt vmcnt(3)" ::: "memory");
  else             asm volatile("s_waitcnt vmcnt(0)" ::: "memory");
}

// ---------------- CSR build ----------------
__global__ __launch_bounds__(1024) void scan_kernel(const int* __restrict__ counts,
                                                    int* __restrict__ offs,
                                                    int* __restrict__ cursor) {
  __shared__ int s[1024];
  int tid = threadIdx.x;
  int local[8];
  int sum = 0;
#pragma unroll
  for (int i = 0; i < 8; ++i) { local[i] = counts[tid * 8 + i]; sum += local[i]; }
  s[tid] = sum;
  __syncthreads();
  for (int d = 1; d < 1024; d <<= 1) {
    int v = (tid >= d) ? s[tid - d] : 0;
    __syncthreads();
    s[tid] += v;
    __syncthreads();
  }
  int base = (tid > 0) ? s[tid - 1] : 0;
#pragma unroll
  for (int i = 0; i < 8; ++i) {
    offs[tid * 8 + i] = base;
    cursor[tid * 8 + i] = base;
    base += local[i];
  }
  if (tid == 1023) offs[8192] = base;
}

__global__ void scatter_kernel(const int* __restrict__ rows, const int* __restrict__ cols,
                               const float* __restrict__ vals, int* cursor,
                               int2* __restrict__ edges) {
  int e = blockIdx.x * 256 + threadIdx.x;
  int slot = atomicAdd(&cursor[rows[e]], 1);
  edges[slot] = make_int2(cols[e], __float_as_int(vals[e]));
}

// ---------------- SpMM (CSR, wave/row, 4-wide 2-stage reg pipeline) ---------
// MODE 0: prod = acc * aux (aux = x, f32)        -> prodb
// MODE 1: prod = acc * elu(aux) (aux = pre1 f32) -> prodb
// MODE 2: no product
template <int MODE>
__global__ __launch_bounds__(256) void spmm_bf(const int* __restrict__ offs,
                                               const int2* __restrict__ edges,
                                               const short* __restrict__ Xbf,
                                               const float* __restrict__ aux,
                                               short* __restrict__ outb,
                                               short* __restrict__ prodb) {
  int row = blockIdx.x * 4 + (threadIdx.x >> 6);
  int lane = threadIdx.x & 63;
  int h0 = lane * 8;
  float acc[8] = {0.f, 0.f, 0.f, 0.f, 0.f, 0.f, 0.f, 0.f};
  int e0 = offs[row], e1 = offs[row + 1];
  int p = e0;

  int2 ma0, ma1, ma2, ma3;
  bf16x8 xa0, xa1, xa2, xa3;

  if (p + 4 <= e1) {
    ma0 = edges[p]; ma1 = edges[p + 1]; ma2 = edges[p + 2]; ma3 = edges[p + 3];
    xa0 = *reinterpret_cast<const bf16x8*>(Xbf + (size_t)ma0.x * HDIM + h0);
    xa1 = *reinterpret_cast<const bf16x8*>(Xbf + (size_t)ma1.x * HDIM + h0);
    xa2 = *reinterpret_cast<const bf16x8*>(Xbf + (size_t)ma2.x * HDIM + h0);
    xa3 = *reinterpret_cast<const bf16x8*>(Xbf + (size_t)ma3.x * HDIM + h0);
    p += 4;
    for (; p + 4 <= e1; p += 4) {
      int2 mb0 = edges[p], mb1 = edges[p + 1], mb2 = edges[p + 2], mb3 = edges[p + 3];
      bf16x8 xb0 = *reinterpret_cast<const bf16x8*>(Xbf + (size_t)mb0.x * HDIM + h0);
      bf16x8 xb1 = *reinterpret_cast<const bf16x8*>(Xbf + (size_t)mb1.x * HDIM + h0);
      bf16x8 xb2 = *reinterpret_cast<const bf16x8*>(Xbf + (size_t)mb2.x * HDIM + h0);
      bf16x8 xb3 = *reinterpret_cast<const bf16x8*>(Xbf + (size_t)mb3.x * HDIM + h0);
      float v0 = __int_as_float(ma0.y), v1 = __int_as_float(ma1.y);
      float v2 = __int_as_float(ma2.y), v3 = __int_as_float(ma3.y);
#pragma unroll
      for (int j = 0; j < 8; ++j) {
        acc[j] = fmaf(v0, bf2f(xa0[j]), acc[j]);
        acc[j] = fmaf(v1, bf2f(xa1[j]), acc[j]);
        acc[j] = fmaf(v2, bf2f(xa2[j]), acc[j]);
        acc[j] = fmaf(v3, bf2f(xa3[j]), acc[j]);
      }
      ma0 = mb0; ma1 = mb1; ma2 = mb2; ma3 = mb3;
      xa0 = xb0; xa1 = xb1; xa2 = xb2; xa3 = xb3;
    }
    {
      float v0 = __int_as_float(ma0.y), v1 = __int_as_float(ma1.y);
      float v2 = __int_as_float(ma2.y), v3 = __int_as_float(ma3.y);
#pragma unroll
      for (int j = 0; j < 8; ++j) {
        acc[j] = fmaf(v0, bf2f(xa0[j]), acc[j]);
        acc[j] = fmaf(v1, bf2f(xa1[j]), acc[j]);
        acc[j] = fmaf(v2, bf2f(xa2[j]), acc[j]);
        acc[j] = fmaf(v3, bf2f(xa3[j]), acc[j]);
      }
    }
  }
  for (; p < e1; ++p) {
    int2 e = edges[p];
    float v = __int_as_float(e.y);
    bf16x8 xr = *reinterpret_cast<const bf16x8*>(Xbf + (size_t)e.x * HDIM + h0);
#pragma unroll
    for (int j = 0; j < 8; ++j) acc[j] = fmaf(v, bf2f(xr[j]), acc[j]);
  }

  bf16x8 o;
#pragma unroll
  for (int j = 0; j < 8; ++j) o[j] = (short)f2bf(acc[j]);
  *reinterpret_cast<bf16x8*>(outb + (size_t)row * 1024 + h0) = o;
  if (MODE != 2) {
    const float4* ap = reinterpret_cast<const float4*>(aux + (size_t)row * HDIM + h0);
    float4 a0 = ap[0], a1 = ap[1];
    float xv[8] = {a0.x, a0.y, a0.z, a0.w, a1.x, a1.y, a1.z, a1.w};
    if (MODE == 1) {
#pragma unroll
      for (int j = 0; j < 8; ++j) xv[j] = xv[j] > 0.f ? xv[j] : expm1f(xv[j]);
    }
    bf16x8 t;
#pragma unroll
    for (int j = 0; j < 8; ++j) t[j] = (short)f2bf(acc[j] * xv[j]);
    *reinterpret_cast<bf16x8*>(prodb + (size_t)row * HDIM + h0) = t;
  }
}

// ---------------- fused prep: hist + x cast + W1/W2 cast + bias -------------
__device__ inline void cast8(const float* src, short* dst) {
  const float4* p = reinterpret_cast<const float4*>(src);
  float4 a = p[0], b = p[1];
  bf16x8 o;
  o[0] = (short)f2bf(a.x); o[1] = (short)f2bf(a.y);
  o[2] = (short)f2bf(a.z); o[3] = (short)f2bf(a.w);
  o[4] = (short)f2bf(b.x); o[5] = (short)f2bf(b.y);
  o[6] = (short)f2bf(b.z); o[7] = (short)f2bf(b.w);
  *reinterpret_cast<bf16x8*>(dst) = o;
}

__global__ void prep_kernel(const int* __restrict__ rows, int* __restrict__ counts,
                            const float* __restrict__ x,
                            const float* __restrict__ W1, const float* __restrict__ W2,
                            const float* __restrict__ b1, const float* __restrict__ b2,
                            short* __restrict__ Xbf, short* __restrict__ Bbuf,
                            float* __restrict__ b12) {
  int b = blockIdx.x;
  if (b < 1024) {                 // hist
    int e = b * 256 + threadIdx.x;
    atomicAdd(&counts[rows[e]], 1);
  } else if (b < 3072) {          // x: 8192x512 -> Xbf (ld 512)
    int t = (b - 1024) * 256 + threadIdx.x;
    int row = t >> 6, c0 = (t & 63) * 8;
    cast8(x + (size_t)row * 512 + c0, Xbf + (size_t)row * 512 + c0);
  } else if (b < 3200) {          // W1 -> Bbuf col 0 (ld 1024)
    int t = (b - 3072) * 256 + threadIdx.x;
    int row = t >> 6, c0 = (t & 63) * 8;
    cast8(W1 + (size_t)row * 512 + c0, Bbuf + (size_t)row * 1024 + c0);
  } else if (b < 3328) {          // W2 -> Bbuf col 512
    int t = (b - 3200) * 256 + threadIdx.x;
    int row = t >> 6, c0 = (t & 63) * 8;
    cast8(W2 + (size_t)row * 512 + c0, Bbuf + (size_t)row * 1024 + 512 + c0);
  } else {                        // bias
    int j = threadIdx.x;
    b12[j] = b1[j] + b2[j];
    b12[j + 256] = b1[j + 256] + b2[j + 256];
  }
}

// ---------------- row L2 normalize + bf16 copy ----------------
__global__ __launch_bounds__(256) void rownorm_kernel(const float* __restrict__ X,
                                                      float* __restrict__ outf,
                                                      short* __restrict__ outb) {
  int row = blockIdx.x * 4 + (threadIdx.x >> 6);
  int lane = threadIdx.x & 63;
  int h0 = lane * 8;
  const float4* p = reinterpret_cast<const float4*>(X + (size_t)row * HDIM + h0);
  float4 a = p[0], b = p[1];
  float s = a.x * a.x + a.y * a.y + a.z * a.z + a.w * a.w +
            b.x * b.x + b.y * b.y + b.z * b.z + b.w * b.w;
#pragma unroll
  for (int off = 1; off < 64; off <<= 1) s += __shfl_xor(s, off, 64);
  float inv = 1.f / fmaxf(sqrtf(s), 1e-12f);
  a.x *= inv; a.y *= inv; a.z *= inv; a.w *= inv;
  b.x *= inv; b.y *= inv; b.z *= inv; b.w *= inv;
  float4* q = reinterpret_cast<float4*>(outf + (size_t)row * HDIM + h0);
  q[0] = a; q[1] = b;
  bf16x8 o;
  o[0] = (short)f2bf(a.x); o[1] = (short)f2bf(a.y);
  o[2] = (short)f2bf(a.z); o[3] = (short)f2bf(a.w);
  o[4] = (short)f2bf(b.x); o[5] = (short)f2bf(b.y);
  o[6] = (short)f2bf(b.z); o[7] = (short)f2bf(b.w);
  *reinterpret_cast<bf16x8*>(outb + (size_t)row * HDIM + h0) = o;
}

// ---------------- layer GEMM: 128x128 tile, 4 waves, K-phase 32, ring -------
// 3-slot ring, stage-after-barrier depth-2, counted vmcnt(4).
// MODE 0: out0 = C + bias (f32, ld N); out1bf = bf16(elu(out0))
// MODE 1: out0 = resid + 0.4*elu(C + bias)
template <int MODE>
__global__ __launch_bounds__(256) void gemm_ring(const short* __restrict__ A,
                                                 const short* __restrict__ B,
                                                 int N, int K, int nbn,
                                                 const float* __restrict__ bias,
                                                 const float* __restrict__ resid,
                                                 float* __restrict__ out0,
                                                 short* __restrict__ out1bf) {
  __shared__ __align__(16) char lds[3 * 16384];
  int NK = K >> 5;

  int q = gridDim.x >> 3;
  int id = (blockIdx.x & 7) * q + (blockIdx.x >> 3);
  int bn = (id % nbn) * 128;
  int bm = (id / nbn) * 128;

  int tid = threadIdx.x;
  int wid = tid >> 6;
  int lane = tid & 63;
  int wm = wid >> 1, wn = wid & 1;
  int rlo = lane & 15;
  int khi = lane >> 4;
  int wbase = wid * 1024;

  size_t ldkB = (size_t)K * 2;
  const char* Ab = (const char*)A + (size_t)bm * ldkB;
  const char* Bb = (const char*)B + (size_t)bn * ldkB;
  int r4 = tid >> 2, c4 = tid & 3;

  f32x4 zero = {0.f, 0.f, 0.f, 0.f};
  f32x4 acc[4][4];
#pragma unroll
  for (int m = 0; m < 4; ++m)
#pragma unroll
    for (int n = 0; n < 4; ++n) acc[m][n] = zero;

  auto stage = [&](int s) {
    char* slot = lds + (s % 3) * 16384;
    size_t go = (size_t)s * 64 + c4 * 16;
    gload16(Ab + (size_t)r4 * ldkB + go,         slot + wbase);
    gload16(Ab + (size_t)(r4 + 64) * ldkB + go,  slot + 4096 + wbase);
    gload16(Bb + (size_t)r4 * ldkB + go,         slot + 8192 + wbase);
    gload16(Bb + (size_t)(r4 + 64) * ldkB + go,  slot + 12288 + wbase);
  };

  stage(0);
  stage(1);

  for (int s = 0; s < NK; ++s) {
    wait_vmcnt_c((s + 1 < NK) ? 4 : 0);
    __builtin_amdgcn_s_barrier();
    __builtin_amdgcn_sched_barrier(0);
    if (s + 2 < NK) stage(s + 2);

    const char* slot = lds + (s % 3) * 16384;
    bf16x8 av[4], bv[4];
#pragma unroll
    for (int m = 0; m < 4; ++m)
      av[m] = *reinterpret_cast<const bf16x8*>(
          slot + (wm * 64 + m * 16 + rlo) * 64 + khi * 16);
#pragma unroll
    for (int n = 0; n < 4; ++n)
      bv[n] = *reinterpret_cast<const bf16x8*>(
          slot + 8192 + (wn * 64 + n * 16 + rlo) * 64 + khi * 16);

    __builtin_amdgcn_s_setprio(1);
#pragma unroll
    for (int m = 0; m < 4; ++m)
#pragma unroll
      for (int n = 0; n < 4; ++n)
        acc[m][n] = __builtin_amdgcn_mfma_f32_16x16x32_bf16(av[m], bv[n], acc[m][n], 0, 0, 0);
    __builtin_amdgcn_s_setprio(0);
  }

  int obm = bm + wm * 64;
  int obn = bn + wn * 64;
  int crow = khi * 4;
#pragma unroll
  for (int n = 0; n < 4; ++n) {
    int c = obn + n * 16 + rlo;
    float bc = bias[c];
#pragma unroll
    for (int m = 0; m < 4; ++m) {
#pragma unroll
      for (int v = 0; v < 4; ++v) {
        int r = obm + m * 16 + crow + v;
        size_t idx = (size_t)r * N + c;
        float val = acc[m][n][v];
        if (MODE == 0) {
          float pvl = val + bc;
          out0[idx] = pvl;
          float e = pvl > 0.f ? pvl : expm1f(pvl);
          out1bf[idx] = (short)f2bf(e);
        } else {
          float pvl = val + bc;
          out0[idx] = resid[idx] + 0.4f * (pvl > 0.f ? pvl : expm1f(pvl));
        }
      }
    }
  }
}

// ---------------- gram: m201-faithful 8-phase, 256x256, 8 waves 128x64 ------
// out = relu(H H^T). 4-slot ring of 32KB "units" (one K-32 slice: panels
// A-half0/A-half1/B-half0/B-half1, 4 G-calls of 8KB each). Step s consumes
// units 2s (phases 0-1) and 2s+1 (phases 2-3); phases stage units 2s+3/2s+4
// (2 calls/phase). Counted vmcnt(8) at odd phases: newest-8 outstanding =
// exactly the 2 legitimately-in-flight units, so the consumed unit is always
// retired. Slot writes always occur after the consuming phase's closing
// barrier (reuse distance 3 mod 4 / 2 mod 4) -> race-free.
// Panels are [128 rows][64B] -> b128 reads spread 8 dwords/bank (optimal,
// no swizzle needed; staging stays linear per both-sides-or-neither rule).
__global__ __launch_bounds__(512, 1) void gram8p(const short* __restrict__ H,
                                                 float* __restrict__ out) {
  __shared__ __align__(16) char lds[131072];   // 4 slots x 32KB

  // XCD swizzle (1024 blocks, 128/XCD) + 4x4 tile supertiles
  int id = (blockIdx.x & 7) * 128 + (blockIdx.x >> 3);
  int st = id >> 4, wt = id & 15;
  int bm = ((st >> 3) * 4 + (wt >> 2)) * 256;
  int bn = ((st & 7) * 4 + (wt & 3)) * 256;

  int tid = threadIdx.x;
  int wid = tid >> 6;
  int lane = tid & 63;
  int wr = wid >> 2;                 // 0..1 (M half: rows wr*128..+127)
  int wc = wid & 3;                  // 0..3 (N quarter: cols wc*64..+63)
  int rlo = lane & 15;
  int khi = lane >> 4;

  const char* Hb = (const char*)H;
  size_t abase = (size_t)bm * 1024;
  size_t bbase = (size_t)bn * 1024;
  int r4 = tid >> 2, c4 = tid & 3;

  // one 8KB G-call: unit u (K-32 slice, k bytes [u*64, u*64+64)),
  // c: 0=A rows 0-127, 1=A rows 128-255, 2=B rows 0-127, 3=B rows 128-255
  auto call = [&](int u, int c) {
    size_t base = (c < 2) ? abase : bbase;
    int row0 = (c & 1) << 7;
    const char* src = Hb + base + (size_t)(row0 + r4) * 1024 + (size_t)u * 64 + c4 * 16;
    char* dst = lds + ((u & 3) << 15) + (c << 13) + tid * 16;
    gload16(src, dst);
  };

  f32x4 zero = {0.f, 0.f, 0.f, 0.f};
  f32x4 acc[8][4];
#pragma unroll
  for (int m = 0; m < 8; ++m)
#pragma unroll
    for (int n = 0; n < 4; ++n) acc[m][n] = zero;

  // prologue: units 0,1,2 staged; confirm unit 0 (newest 8 = units 1,2)
#pragma unroll
  for (int u = 0; u < 3; ++u)
#pragma unroll
    for (int c = 0; c < 4; ++c) call(u, c);
  wait_vmcnt_c(8);
  __builtin_amdgcn_s_barrier();
  __builtin_amdgcn_sched_barrier(0);

  bf16x8 av[4], bv[4];

#pragma unroll 1
  for (int s = 0; s < 8; ++s) {
#pragma unroll
    for (int p = 0; p < 4; ++p) {
      int u = 2 * s + (p >> 1);            // consumed unit
      int w = 2 * s + 3 + (p >> 1);        // staged unit
      int cb = (p & 1) * 2;
      if (w < 16) { call(w, cb); call(w, cb + 1); }

      const char* slot = lds + ((u & 3) << 15);
      int h = p & 1;
#pragma unroll
      for (int i = 0; i < 4; ++i)
        av[i] = *reinterpret_cast<const bf16x8*>(
            slot + (wr << 13) + ((h * 4 + i) * 16 + rlo) * 64 + khi * 16);
      if (h == 0) {
#pragma unroll
        for (int n = 0; n < 4; ++n)
          bv[n] = *reinterpret_cast<const bf16x8*>(
              slot + 16384 + ((wc >> 1) << 13) +
              ((wc & 1) * 64 + n * 16 + rlo) * 64 + khi * 16);
      }

      if (p == 1) wait_vmcnt_c((s <= 6) ? 8 : 0);          // confirm unit 2s+1
      if (p == 3) wait_vmcnt_c((s <= 5) ? 8 : (s == 6 ? 4 : 0)); // confirm 2s+2
      __builtin_amdgcn_s_barrier();
      __builtin_amdgcn_sched_barrier(0);

      __builtin_amdgcn_s_setprio(1);
#pragma unroll
      for (int i = 0; i < 4; ++i)
#pragma unroll
        for (int n = 0; n < 4; ++n)
          acc[h * 4 + i][n] =
              __builtin_amdgcn_mfma_f32_16x16x32_bf16(av[i], bv[n], acc[h * 4 + i][n], 0, 0, 0);
      __builtin_amdgcn_s_setprio(0);
      __builtin_amdgcn_s_barrier();
      __builtin_amdgcn_sched_barrier(0);
    }
  }

  int obm = bm + wr * 128;
  int obn = bn + wc * 64;
  int crow = khi * 4;
#pragma unroll
  for (int m = 0; m < 8; ++m) {
#pragma unroll
    for (int n = 0; n < 4; ++n) {
      int c = obn + n * 16 + rlo;
#pragma unroll
      for (int v = 0; v < 4; ++v) {
        int r = obm + m * 16 + crow + v;
        float val = acc[m][n][v];
        out[(size_t)r * N_NODES + c] = val > 0.f ? val : 0.f;
      }
    }
  }
}

extern "C" void kernel_launch(void* const* d_in, const int* in_sizes, int n_in,
                              void* d_out, int out_size, void* d_ws, size_t ws_size,
                              hipStream_t stream) {
  const float* x  = (const float*)d_in[0];
  const int* rows = (const int*)d_in[1];
  const int* cols = (const int*)d_in[2];
  const float* vals = (const float*)d_in[3];
  const float* W1 = (const float*)d_in[4];
  const float* b1 = (const float*)d_in[5];
  const float* W2 = (const float*)d_in[6];
  const float* b2 = (const float*)d_in[7];

  float* out_adj = (float*)d_out;
  float* out_hid = out_adj + (size_t)N_NODES * N_NODES;

  char* w = (char*)d_ws;
  size_t off = 0;
  auto alloc = [&](size_t bytes) -> void* {
    void* p = w + off;
    off += (bytes + 255) & ~(size_t)255;
    return p;
  };
  int* counts   = (int*)alloc(8192 * sizeof(int));
  int* offs     = (int*)alloc(8193 * sizeof(int));
  int* cursor   = (int*)alloc(8192 * sizeof(int));
  int2* edges   = (int2*)alloc((size_t)NEDGE * sizeof(int2));
  float* b12    = (float*)alloc(HDIM * sizeof(float));
  short* Xbf    = (short*)alloc((size_t)N_NODES * HDIM * sizeof(short));
  short* Tbf    = (short*)alloc((size_t)N_NODES * HDIM * sizeof(short));
  short* Abuf   = (short*)alloc((size_t)N_NODES * 1024 * sizeof(short));
  short* Bbuf   = (short*)alloc((size_t)512 * 1024 * sizeof(short));
  float* pre1   = (float*)alloc((size_t)N_NODES * HDIM * sizeof(float));
  float* Hf     = (float*)alloc((size_t)N_NODES * HDIM * sizeof(float));
  short* Hbuf   = (short*)alloc((size_t)N_NODES * HDIM * sizeof(short));

  // CSR build + prep (hist fused into prep)
  hipMemsetAsync(counts, 0, 8192 * sizeof(int), stream);
  prep_kernel<<<3329, 256, 0, stream>>>(rows, counts, x, W1, W2, b1, b2, Xbf, Bbuf, b12);
  scan_kernel<<<1, 1024, 0, stream>>>(counts, offs, cursor);
  scatter_kernel<<<NEDGE / 256, 256, 0, stream>>>(rows, cols, vals, cursor, edges);

  // ---- layer 1 ----
  spmm_bf<0><<<2048, 256, 0, stream>>>(offs, edges, Xbf, x, Abuf, Tbf);
  spmm_bf<2><<<2048, 256, 0, stream>>>(offs, edges, Tbf, nullptr, Abuf + 512, nullptr);
  gemm_ring<0><<<256, 256, 0, stream>>>(Abuf, Bbuf, 512, 1024, 4, b12, nullptr, pre1, Xbf);

  // ---- layer 2 ----
  spmm_bf<1><<<2048, 256, 0, stream>>>(offs, edges, Xbf, pre1, Abuf, Tbf);
  spmm_bf<2><<<2048, 256, 0, stream>>>(offs, edges, Tbf, nullptr, Abuf + 512, nullptr);
  gemm_ring<1><<<256, 256, 0, stream>>>(Abuf, Bbuf, 512, 1024, 4, b12, pre1, Hf, nullptr);

  // ---- decoder ----
  rownorm_kernel<<<2048, 256, 0, stream>>>(Hf, out_hid, Hbuf);
  gram8p<<<1024, 512, 0, stream>>>(Hbuf, out_adj);
}

// Round 14
// 315.817 us; speedup vs baseline: 1.0894x; 1.0894x over previous
//
#include <hip/hip_runtime.h>

#define N_NODES 8192
#define HDIM    512
#define NEDGE   262144

typedef __attribute__((ext_vector_type(8))) short bf16x8;
typedef __attribute__((ext_vector_type(4))) float f32x4;

__device__ inline unsigned short f2bf(float f) {
  unsigned u = __float_as_uint(f);
  unsigned r = (u + 0x7FFFu + ((u >> 16) & 1u)) >> 16;
  return (unsigned short)r;
}
__device__ inline float bf2f(short s) {
  return __uint_as_float(((unsigned)(unsigned short)s) << 16);
}

__device__ inline void gload16(const void* g, void* l) {
  __builtin_amdgcn_global_load_lds(
      (const __attribute__((address_space(1))) unsigned*)g,
      (__attribute__((address_space(3))) unsigned*)l, 16, 0, 0);
}

__device__ inline void wait_vmcnt_c(int n) {
  if (n == 4)      asm volatile("s_waitcnt vmcnt(4)" ::: "memory");
  else if (n == 3) asm volatile("s_waitcnt vmcnt(3)" ::: "memory");
  else             asm volatile("s_waitcnt vmcnt(0)" ::: "memory");
}

// ---------------- CSR build ----------------
__global__ __launch_bounds__(1024) void scan_kernel(const int* __restrict__ counts,
                                                    int* __restrict__ offs,
                                                    int* __restrict__ cursor) {
  __shared__ int s[1024];
  int tid = threadIdx.x;
  int local[8];
  int sum = 0;
#pragma unroll
  for (int i = 0; i < 8; ++i) { local[i] = counts[tid * 8 + i]; sum += local[i]; }
  s[tid] = sum;
  __syncthreads();
  for (int d = 1; d < 1024; d <<= 1) {
    int v = (tid >= d) ? s[tid - d] : 0;
    __syncthreads();
    s[tid] += v;
    __syncthreads();
  }
  int base = (tid > 0) ? s[tid - 1] : 0;
#pragma unroll
  for (int i = 0; i < 8; ++i) {
    offs[tid * 8 + i] = base;
    cursor[tid * 8 + i] = base;
    base += local[i];
  }
  if (tid == 1023) offs[8192] = base;
}

__global__ void scatter_kernel(const int* __restrict__ rows, const int* __restrict__ cols,
                               const float* __restrict__ vals, int* cursor,
                               int2* __restrict__ edges) {
  int e = blockIdx.x * 256 + threadIdx.x;
  int slot = atomicAdd(&cursor[rows[e]], 1);
  edges[slot] = make_int2(cols[e], __float_as_int(vals[e]));
}

// ---------------- SpMM (CSR, wave/row, 4-wide 2-stage reg pipeline) ---------
// MODE 0: prod = acc * aux (aux = x, f32)        -> prodb
// MODE 1: prod = acc * elu(aux) (aux = pre1 f32) -> prodb
// MODE 2: no product
template <int MODE>
__global__ __launch_bounds__(256) void spmm_bf(const int* __restrict__ offs,
                                               const int2* __restrict__ edges,
                                               const short* __restrict__ Xbf,
                                               const float* __restrict__ aux,
                                               short* __restrict__ outb,
                                               short* __restrict__ prodb) {
  int row = blockIdx.x * 4 + (threadIdx.x >> 6);
  int lane = threadIdx.x & 63;
  int h0 = lane * 8;
  float acc[8] = {0.f, 0.f, 0.f, 0.f, 0.f, 0.f, 0.f, 0.f};
  int e0 = offs[row], e1 = offs[row + 1];
  int p = e0;

  int2 ma0, ma1, ma2, ma3;
  bf16x8 xa0, xa1, xa2, xa3;

  if (p + 4 <= e1) {
    ma0 = edges[p]; ma1 = edges[p + 1]; ma2 = edges[p + 2]; ma3 = edges[p + 3];
    xa0 = *reinterpret_cast<const bf16x8*>(Xbf + (size_t)ma0.x * HDIM + h0);
    xa1 = *reinterpret_cast<const bf16x8*>(Xbf + (size_t)ma1.x * HDIM + h0);
    xa2 = *reinterpret_cast<const bf16x8*>(Xbf + (size_t)ma2.x * HDIM + h0);
    xa3 = *reinterpret_cast<const bf16x8*>(Xbf + (size_t)ma3.x * HDIM + h0);
    p += 4;
    for (; p + 4 <= e1; p += 4) {
      int2 mb0 = edges[p], mb1 = edges[p + 1], mb2 = edges[p + 2], mb3 = edges[p + 3];
      bf16x8 xb0 = *reinterpret_cast<const bf16x8*>(Xbf + (size_t)mb0.x * HDIM + h0);
      bf16x8 xb1 = *reinterpret_cast<const bf16x8*>(Xbf + (size_t)mb1.x * HDIM + h0);
      bf16x8 xb2 = *reinterpret_cast<const bf16x8*>(Xbf + (size_t)mb2.x * HDIM + h0);
      bf16x8 xb3 = *reinterpret_cast<const bf16x8*>(Xbf + (size_t)mb3.x * HDIM + h0);
      float v0 = __int_as_float(ma0.y), v1 = __int_as_float(ma1.y);
      float v2 = __int_as_float(ma2.y), v3 = __int_as_float(ma3.y);
#pragma unroll
      for (int j = 0; j < 8; ++j) {
        acc[j] = fmaf(v0, bf2f(xa0[j]), acc[j]);
        acc[j] = fmaf(v1, bf2f(xa1[j]), acc[j]);
        acc[j] = fmaf(v2, bf2f(xa2[j]), acc[j]);
        acc[j] = fmaf(v3, bf2f(xa3[j]), acc[j]);
      }
      ma0 = mb0; ma1 = mb1; ma2 = mb2; ma3 = mb3;
      xa0 = xb0; xa1 = xb1; xa2 = xb2; xa3 = xb3;
    }
    {
      float v0 = __int_as_float(ma0.y), v1 = __int_as_float(ma1.y);
      float v2 = __int_as_float(ma2.y), v3 = __int_as_float(ma3.y);
#pragma unroll
      for (int j = 0; j < 8; ++j) {
        acc[j] = fmaf(v0, bf2f(xa0[j]), acc[j]);
        acc[j] = fmaf(v1, bf2f(xa1[j]), acc[j]);
        acc[j] = fmaf(v2, bf2f(xa2[j]), acc[j]);
        acc[j] = fmaf(v3, bf2f(xa3[j]), acc[j]);
      }
    }
  }
  for (; p < e1; ++p) {
    int2 e = edges[p];
    float v = __int_as_float(e.y);
    bf16x8 xr = *reinterpret_cast<const bf16x8*>(Xbf + (size_t)e.x * HDIM + h0);
#pragma unroll
    for (int j = 0; j < 8; ++j) acc[j] = fmaf(v, bf2f(xr[j]), acc[j]);
  }

  bf16x8 o;
#pragma unroll
  for (int j = 0; j < 8; ++j) o[j] = (short)f2bf(acc[j]);
  *reinterpret_cast<bf16x8*>(outb + (size_t)row * 1024 + h0) = o;
  if (MODE != 2) {
    const float4* ap = reinterpret_cast<const float4*>(aux + (size_t)row * HDIM + h0);
    float4 a0 = ap[0], a1 = ap[1];
    float xv[8] = {a0.x, a0.y, a0.z, a0.w, a1.x, a1.y, a1.z, a1.w};
    if (MODE == 1) {
#pragma unroll
      for (int j = 0; j < 8; ++j) xv[j] = xv[j] > 0.f ? xv[j] : expm1f(xv[j]);
    }
    bf16x8 t;
#pragma unroll
    for (int j = 0; j < 8; ++j) t[j] = (short)f2bf(acc[j] * xv[j]);
    *reinterpret_cast<bf16x8*>(prodb + (size_t)row * HDIM + h0) = t;
  }
}

// ---------------- fused prep: hist + x cast + W1/W2 cast + bias -------------
__device__ inline void cast8(const float* src, short* dst) {
  const float4* p = reinterpret_cast<const float4*>(src);
  float4 a = p[0], b = p[1];
  bf16x8 o;
  o[0] = (short)f2bf(a.x); o[1] = (short)f2bf(a.y);
  o[2] = (short)f2bf(a.z); o[3] = (short)f2bf(a.w);
  o[4] = (short)f2bf(b.x); o[5] = (short)f2bf(b.y);
  o[6] = (short)f2bf(b.z); o[7] = (short)f2bf(b.w);
  *reinterpret_cast<bf16x8*>(dst) = o;
}

__global__ void prep_kernel(const int* __restrict__ rows, int* __restrict__ counts,
                            const float* __restrict__ x,
                            const float* __restrict__ W1, const float* __restrict__ W2,
                            const float* __restrict__ b1, const float* __restrict__ b2,
                            short* __restrict__ Xbf, short* __restrict__ Bbuf,
                            float* __restrict__ b12) {
  int b = blockIdx.x;
  if (b < 1024) {                 // hist
    int e = b * 256 + threadIdx.x;
    atomicAdd(&counts[rows[e]], 1);
  } else if (b < 3072) {          // x: 8192x512 -> Xbf (ld 512)
    int t = (b - 1024) * 256 + threadIdx.x;
    int row = t >> 6, c0 = (t & 63) * 8;
    cast8(x + (size_t)row * 512 + c0, Xbf + (size_t)row * 512 + c0);
  } else if (b < 3200) {          // W1 -> Bbuf col 0 (ld 1024)
    int t = (b - 3072) * 256 + threadIdx.x;
    int row = t >> 6, c0 = (t & 63) * 8;
    cast8(W1 + (size_t)row * 512 + c0, Bbuf + (size_t)row * 1024 + c0);
  } else if (b < 3328) {          // W2 -> Bbuf col 512
    int t = (b - 3200) * 256 + threadIdx.x;
    int row = t >> 6, c0 = (t & 63) * 8;
    cast8(W2 + (size_t)row * 512 + c0, Bbuf + (size_t)row * 1024 + 512 + c0);
  } else {                        // bias
    int j = threadIdx.x;
    b12[j] = b1[j] + b2[j];
    b12[j + 256] = b1[j + 256] + b2[j + 256];
  }
}

// ---------------- row L2 normalize + bf16 copy ----------------
__global__ __launch_bounds__(256) void rownorm_kernel(const float* __restrict__ X,
                                                      float* __restrict__ outf,
                                                      short* __restrict__ outb) {
  int row = blockIdx.x * 4 + (threadIdx.x >> 6);
  int lane = threadIdx.x & 63;
  int h0 = lane * 8;
  const float4* p = reinterpret_cast<const float4*>(X + (size_t)row * HDIM + h0);
  float4 a = p[0], b = p[1];
  float s = a.x * a.x + a.y * a.y + a.z * a.z + a.w * a.w +
            b.x * b.x + b.y * b.y + b.z * b.z + b.w * b.w;
#pragma unroll
  for (int off = 1; off < 64; off <<= 1) s += __shfl_xor(s, off, 64);
  float inv = 1.f / fmaxf(sqrtf(s), 1e-12f);
  a.x *= inv; a.y *= inv; a.z *= inv; a.w *= inv;
  b.x *= inv; b.y *= inv; b.z *= inv; b.w *= inv;
  float4* q = reinterpret_cast<float4*>(outf + (size_t)row * HDIM + h0);
  q[0] = a; q[1] = b;
  bf16x8 o;
  o[0] = (short)f2bf(a.x); o[1] = (short)f2bf(a.y);
  o[2] = (short)f2bf(a.z); o[3] = (short)f2bf(a.w);
  o[4] = (short)f2bf(b.x); o[5] = (short)f2bf(b.y);
  o[6] = (short)f2bf(b.z); o[7] = (short)f2bf(b.w);
  *reinterpret_cast<bf16x8*>(outb + (size_t)row * HDIM + h0) = o;
}

// ---------------- layer GEMM: 128x128 tile, 4 waves, K-phase 32, ring -------
// 3-slot ring, stage-after-barrier depth-2, counted vmcnt(4).
// MODE 0: out0 = C + bias (f32, ld N); out1bf = bf16(elu(out0))
// MODE 1: out0 = resid + 0.4*elu(C + bias)
template <int MODE>
__global__ __launch_bounds__(256) void gemm_ring(const short* __restrict__ A,
                                                 const short* __restrict__ B,
                                                 int N, int K, int nbn,
                                                 const float* __restrict__ bias,
                                                 const float* __restrict__ resid,
                                                 float* __restrict__ out0,
                                                 short* __restrict__ out1bf) {
  __shared__ __align__(16) char lds[3 * 16384];
  int NK = K >> 5;

  int q = gridDim.x >> 3;
  int id = (blockIdx.x & 7) * q + (blockIdx.x >> 3);
  int bn = (id % nbn) * 128;
  int bm = (id / nbn) * 128;

  int tid = threadIdx.x;
  int wid = tid >> 6;
  int lane = tid & 63;
  int wm = wid >> 1, wn = wid & 1;
  int rlo = lane & 15;
  int khi = lane >> 4;
  int wbase = wid * 1024;

  size_t ldkB = (size_t)K * 2;
  const char* Ab = (const char*)A + (size_t)bm * ldkB;
  const char* Bb = (const char*)B + (size_t)bn * ldkB;
  int r4 = tid >> 2, c4 = tid & 3;

  f32x4 zero = {0.f, 0.f, 0.f, 0.f};
  f32x4 acc[4][4];
#pragma unroll
  for (int m = 0; m < 4; ++m)
#pragma unroll
    for (int n = 0; n < 4; ++n) acc[m][n] = zero;

  auto stage = [&](int s) {
    char* slot = lds + (s % 3) * 16384;
    size_t go = (size_t)s * 64 + c4 * 16;
    gload16(Ab + (size_t)r4 * ldkB + go,         slot + wbase);
    gload16(Ab + (size_t)(r4 + 64) * ldkB + go,  slot + 4096 + wbase);
    gload16(Bb + (size_t)r4 * ldkB + go,         slot + 8192 + wbase);
    gload16(Bb + (size_t)(r4 + 64) * ldkB + go,  slot + 12288 + wbase);
  };

  stage(0);
  stage(1);

  for (int s = 0; s < NK; ++s) {
    wait_vmcnt_c((s + 1 < NK) ? 4 : 0);
    __builtin_amdgcn_s_barrier();
    __builtin_amdgcn_sched_barrier(0);
    if (s + 2 < NK) stage(s + 2);

    const char* slot = lds + (s % 3) * 16384;
    bf16x8 av[4], bv[4];
#pragma unroll
    for (int m = 0; m < 4; ++m)
      av[m] = *reinterpret_cast<const bf16x8*>(
          slot + (wm * 64 + m * 16 + rlo) * 64 + khi * 16);
#pragma unroll
    for (int n = 0; n < 4; ++n)
      bv[n] = *reinterpret_cast<const bf16x8*>(
          slot + 8192 + (wn * 64 + n * 16 + rlo) * 64 + khi * 16);

    __builtin_amdgcn_s_setprio(1);
#pragma unroll
    for (int m = 0; m < 4; ++m)
#pragma unroll
      for (int n = 0; n < 4; ++n)
        acc[m][n] = __builtin_amdgcn_mfma_f32_16x16x32_bf16(av[m], bv[n], acc[m][n], 0, 0, 0);
    __builtin_amdgcn_s_setprio(0);
  }

  int obm = bm + wm * 64;
  int obn = bn + wn * 64;
  int crow = khi * 4;
#pragma unroll
  for (int n = 0; n < 4; ++n) {
    int c = obn + n * 16 + rlo;
    float bc = bias[c];
#pragma unroll
    for (int m = 0; m < 4; ++m) {
#pragma unroll
      for (int v = 0; v < 4; ++v) {
        int r = obm + m * 16 + crow + v;
        size_t idx = (size_t)r * N + c;
        float val = acc[m][n][v];
        if (MODE == 0) {
          float pvl = val + bc;
          out0[idx] = pvl;
          float e = pvl > 0.f ? pvl : expm1f(pvl);
          out1bf[idx] = (short)f2bf(e);
        } else {
          float pvl = val + bc;
          out0[idx] = resid[idx] + 0.4f * (pvl > 0.f ? pvl : expm1f(pvl));
        }
      }
    }
  }
}

// ---------------- gram: 128x256 tile, 8 waves (2x4), 64x64/wave, ring -------
// (R8 known-good) 3-slot 24KB ring, stage-after-barrier depth-2,
// counted vmcnt(3), setprio around MFMA, 1 barrier/phase, 2 blocks/CU.
__global__ __launch_bounds__(512, 4) void gram256(const short* __restrict__ H,
                                                  float* __restrict__ out) {
  __shared__ __align__(16) char lds[3 * 24576];
  const int NK = HDIM / 32;          // 16

  int id = (blockIdx.x & 7) * 256 + (blockIdx.x >> 3);
  int st = id >> 4, wt = id & 15;
  int bm = ((st >> 3) * 4 + (wt >> 2)) * 128;
  int bn = ((st & 7) * 4 + (wt & 3)) * 256;

  int tid = threadIdx.x;
  int wid = tid >> 6;
  int lane = tid & 63;
  int wr = wid >> 2;
  int wc = wid & 3;
  int rlo = lane & 15;
  int khi = lane >> 4;
  int wbase = wid * 1024;

  const char* Ab = (const char*)H + (size_t)bm * 1024;
  const char* Bb = (const char*)H + (size_t)bn * 1024;
  int r4 = tid >> 2, c4 = tid & 3;

  f32x4 zero = {0.f, 0.f, 0.f, 0.f};
  f32x4 acc[4][4];
#pragma unroll
  for (int m = 0; m < 4; ++m)
#pragma unroll
    for (int n = 0; n < 4; ++n) acc[m][n] = zero;

  auto stage = [&](int s) {
    char* slot = lds + (s % 3) * 24576;
    size_t go = (size_t)s * 64 + c4 * 16;
    gload16(Ab + (size_t)r4 * 1024 + go,         slot + wbase);
    gload16(Bb + (size_t)r4 * 1024 + go,         slot + 8192 + wbase);
    gload16(Bb + (size_t)(r4 + 128) * 1024 + go, slot + 16384 + wbase);
  };

  stage(0);
  stage(1);

  for (int s = 0; s < NK; ++s) {
    wait_vmcnt_c((s + 1 < NK) ? 3 : 0);
    __builtin_amdgcn_s_barrier();
    __builtin_amdgcn_sched_barrier(0);
    if (s + 2 < NK) stage(s + 2);

    const char* slot = lds + (s % 3) * 24576;
    bf16x8 av[4], bv[4];
#pragma unroll
    for (int m = 0; m < 4; ++m)
      av[m] = *reinterpret_cast<const bf16x8*>(
          slot + (wr * 64 + m * 16 + rlo) * 64 + khi * 16);
#pragma unroll
    for (int n = 0; n < 4; ++n)
      bv[n] = *reinterpret_cast<const bf16x8*>(
          slot + 8192 + (wc * 64 + n * 16 + rlo) * 64 + khi * 16);

    __builtin_amdgcn_s_setprio(1);
#pragma unroll
    for (int m = 0; m < 4; ++m)
#pragma unroll
      for (int n = 0; n < 4; ++n)
        acc[m][n] = __builtin_amdgcn_mfma_f32_16x16x32_bf16(av[m], bv[n], acc[m][n], 0, 0, 0);
    __builtin_amdgcn_s_setprio(0);
  }

  int obm = bm + wr * 64;
  int obn = bn + wc * 64;
  int crow = khi * 4;
#pragma unroll
  for (int m = 0; m < 4; ++m) {
#pragma unroll
    for (int n = 0; n < 4; ++n) {
      int c = obn + n * 16 + rlo;
#pragma unroll
      for (int v = 0; v < 4; ++v) {
        int r = obm + m * 16 + crow + v;
        float val = acc[m][n][v];
        out[(size_t)r * N_NODES + c] = val > 0.f ? val : 0.f;
      }
    }
  }
}

extern "C" void kernel_launch(void* const* d_in, const int* in_sizes, int n_in,
                              void* d_out, int out_size, void* d_ws, size_t ws_size,
                              hipStream_t stream) {
  const float* x  = (const float*)d_in[0];
  const int* rows = (const int*)d_in[1];
  const int* cols = (const int*)d_in[2];
  const float* vals = (const float*)d_in[3];
  const float* W1 = (const float*)d_in[4];
  const float* b1 = (const float*)d_in[5];
  const float* W2 = (const float*)d_in[6];
  const float* b2 = (const float*)d_in[7];

  float* out_adj = (float*)d_out;
  float* out_hid = out_adj + (size_t)N_NODES * N_NODES;

  char* w = (char*)d_ws;
  size_t off = 0;
  auto alloc = [&](size_t bytes) -> void* {
    void* p = w + off;
    off += (bytes + 255) & ~(size_t)255;
    return p;
  };
  int* counts   = (int*)alloc(8192 * sizeof(int));
  int* offs     = (int*)alloc(8193 * sizeof(int));
  int* cursor   = (int*)alloc(8192 * sizeof(int));
  int2* edges   = (int2*)alloc((size_t)NEDGE * sizeof(int2));
  float* b12    = (float*)alloc(HDIM * sizeof(float));
  short* Xbf    = (short*)alloc((size_t)N_NODES * HDIM * sizeof(short));
  short* Tbf    = (short*)alloc((size_t)N_NODES * HDIM * sizeof(short));
  short* Abuf   = (short*)alloc((size_t)N_NODES * 1024 * sizeof(short));
  short* Bbuf   = (short*)alloc((size_t)512 * 1024 * sizeof(short));
  float* pre1   = (float*)alloc((size_t)N_NODES * HDIM * sizeof(float));
  float* Hf     = (float*)alloc((size_t)N_NODES * HDIM * sizeof(float));
  short* Hbuf   = (short*)alloc((size_t)N_NODES * HDIM * sizeof(short));

  // CSR build + prep (hist fused into prep)
  hipMemsetAsync(counts, 0, 8192 * sizeof(int), stream);
  prep_kernel<<<3329, 256, 0, stream>>>(rows, counts, x, W1, W2, b1, b2, Xbf, Bbuf, b12);
  scan_kernel<<<1, 1024, 0, stream>>>(counts, offs, cursor);
  scatter_kernel<<<NEDGE / 256, 256, 0, stream>>>(rows, cols, vals, cursor, edges);

  // ---- layer 1 ----
  spmm_bf<0><<<2048, 256, 0, stream>>>(offs, edges, Xbf, x, Abuf, Tbf);
  spmm_bf<2><<<2048, 256, 0, stream>>>(offs, edges, Tbf, nullptr, Abuf + 512, nullptr);
  gemm_ring<0><<<256, 256, 0, stream>>>(Abuf, Bbuf, 512, 1024, 4, b12, nullptr, pre1, Xbf);

  // ---- layer 2 ----
  spmm_bf<1><<<2048, 256, 0, stream>>>(offs, edges, Xbf, pre1, Abuf, Tbf);
  spmm_bf<2><<<2048, 256, 0, stream>>>(offs, edges, Tbf, nullptr, Abuf + 512, nullptr);
  gemm_ring<1><<<256, 256, 0, stream>>>(Abuf, Bbuf, 512, 1024, 4, b12, pre1, Hf, nullptr);

  // ---- decoder ----
  rownorm_kernel<<<2048, 256, 0, stream>>>(Hf, out_hid, Hbuf);
  gram256<<<2048, 512, 0, stream>>>(Hbuf, out_adj);
}